// Round 4
// baseline (352.473 us; speedup 1.0000x reference)
//
#include <hip/hip_runtime.h>

typedef short  bf16x8 __attribute__((ext_vector_type(8)));
typedef float  f32x4  __attribute__((ext_vector_type(4)));

#define NA   32
#define HID  128
#define TPB  8
#define KSTR 136   // ushort stride, 272B rows: 16B-aligned for b128 reads

__device__ __forceinline__ unsigned short f2bf(float f) {
  unsigned int u = __float_as_uint(f);
  return (unsigned short)((u + 0x7FFFu + ((u >> 16) & 1u)) >> 16);  // RNE
}
__device__ __forceinline__ float bf2f(unsigned short s) {
  return __uint_as_float(((unsigned int)s) << 16);
}
// LDS-only barrier: does NOT drain vmcnt, so global prefetch loads stay in
// flight across it (all cross-wave hazards in the main loop are LDS).
__device__ __forceinline__ void barrier_lds() {
  asm volatile("" ::: "memory");
  asm volatile("s_waitcnt lgkmcnt(0)" ::: "memory");
  __builtin_amdgcn_s_barrier();
  asm volatile("" ::: "memory");
}

__global__ __launch_bounds__(256, 4) void soft_attn_v4(
    const float* __restrict__ h, const float* __restrict__ msg,
    const float* __restrict__ mask,
    const float* __restrict__ qW, const float* __restrict__ qb,
    const float* __restrict__ kW, const float* __restrict__ kb,
    const float* __restrict__ vW, const float* __restrict__ vb,
    const float* __restrict__ dW, const float* __restrict__ db,
    const float* __restrict__ lnw, const float* __restrict__ lnb,
    float* __restrict__ out)
{
  const int t    = threadIdx.x;
  const int lane = t & 63;
  const int w    = t >> 6;        // wave id; owns output cols [32w, 32w+32)
  const int lm   = lane & 15;
  const int lg   = lane >> 4;
  const int n0   = w * 32;
  const int tok0 = blockIdx.x * TPB;

  __shared__ __align__(16) short          s_msgF[8 * 64 * 8];   // 8 KB  msg A-frags
  __shared__ __align__(16) unsigned short s_k[NA * KSTR];       // 8.5 KB bf16 k
  __shared__ __align__(16) unsigned short s_v[NA * KSTR];       // 8.5 KB bf16 v (relu'd)
  __shared__ __align__(16) float          s_qall[TPB * HID];    // 4 KB
  __shared__ __align__(16) float          s_p[8 * NA];          // 1 KB
  __shared__ __align__(16) short          s_ctxF[4 * 64 * 8];   // 4 KB ctx A-frags
  __shared__ __align__(16) char           s_un[4096];           // 4 KB: hF then dall
  short* s_hF   = (short*)s_un;
  float* s_dall = (float*)s_un;
  // total ~38 KB -> 4 blocks/CU

  // ---- prologue: zero ctxF pads, stage h frags, prefetch msg(token0), Bq ----
  ((unsigned int*)s_ctxF)[t]       = 0u;
  ((unsigned int*)s_ctxF)[t + 256] = 0u;
  {
    bf16x8 sv;
#pragma unroll
    for (int e = 0; e < 8; ++e) sv[e] = 0;
    if (lm < TPB) {
      const float* hp = h + (size_t)(tok0 + lm) * HID + w * 32 + lg * 8;
      const f32x4 x0 = *(const f32x4*)hp;
      const f32x4 x1 = *(const f32x4*)(hp + 4);
#pragma unroll
      for (int e = 0; e < 4; ++e) { sv[e] = (short)f2bf(x0[e]); sv[4 + e] = (short)f2bf(x1[e]); }
    }
    ((bf16x8*)s_hF)[w * 64 + lane] = sv;   // frag f = w (K-slice), slot = kg*16+m
  }
  f32x4 P[2][2];  // msg prefetch regs: frags {w, w+4}
#pragma unroll
  for (int j = 0; j < 2; ++j) {
    const int f = j * 4 + w, mt = f >> 2, ks = f & 3;
    const float* mp = msg + (size_t)tok0 * (NA * HID) + (mt * 16 + lm) * HID + ks * 32 + lg * 8;
    P[j][0] = *(const f32x4*)mp; P[j][1] = *(const f32x4*)(mp + 4);
  }
  {
    // Bq transient inside this scope
    bf16x8 Bq[2][4];
    float qb2[2];
#pragma unroll
    for (int nt = 0; nt < 2; ++nt) {
      const int col = n0 + nt * 16 + lm;
      qb2[nt] = qb[col];
#pragma unroll
      for (int ks = 0; ks < 4; ++ks) {
        bf16x8 bq;
#pragma unroll
        for (int e = 0; e < 8; ++e)
          bq[e] = (short)f2bf(qW[(size_t)(ks * 32 + lg * 8 + e) * HID + col]);
        Bq[nt][ks] = bq;
      }
    }
    __syncthreads();   // hF ready
    f32x4 accq[2];
#pragma unroll
    for (int nt = 0; nt < 2; ++nt) accq[nt] = (f32x4){qb2[nt], qb2[nt], qb2[nt], qb2[nt]};
#pragma unroll
    for (int ks = 0; ks < 4; ++ks) {
      const bf16x8 a = ((const bf16x8*)s_hF)[ks * 64 + lane];
#pragma unroll
      for (int nt = 0; nt < 2; ++nt)
        accq[nt] = __builtin_amdgcn_mfma_f32_16x16x32_bf16(a, Bq[nt][ks], accq[nt], 0, 0, 0);
    }
#pragma unroll
    for (int nt = 0; nt < 2; ++nt)
#pragma unroll
      for (int r = 0; r < 4; ++r) {
        const int row = lg * 4 + r;
        if (row < TPB) s_qall[row * HID + n0 + nt * 16 + lm] = accq[nt][r];
      }
  }

  // ---- persistent k/v weight fragments ----
  bf16x8 Bk[2][4], Bv[2][4];
  float kb2[2], vb2[2];
#pragma unroll
  for (int nt = 0; nt < 2; ++nt) {
    const int col = n0 + nt * 16 + lm;
    kb2[nt] = kb[col]; vb2[nt] = vb[col];
#pragma unroll
    for (int ks = 0; ks < 4; ++ks) {
      bf16x8 bk, bv;
#pragma unroll
      for (int e = 0; e < 8; ++e) {
        const size_t r = (size_t)(ks * 32 + lg * 8 + e) * HID + col;
        bk[e] = (short)f2bf(kW[r]); bv[e] = (short)f2bf(vW[r]);
      }
      Bk[nt][ks] = bk; Bv[nt][ks] = bv;
    }
  }

  // ---- main loop: stage | B1 | kv-MFMA, prefetch(it+1) | B2 | scores | B3 | PV ----
#pragma unroll 1
  for (int it = 0; it < TPB; ++it) {
    const int tok = tok0 + it;

    // stage msgF from P (b128 writes, stride-1)
#pragma unroll
    for (int j = 0; j < 2; ++j) {
      const int f = j * 4 + w;
      bf16x8 sv;
#pragma unroll
      for (int e = 0; e < 4; ++e) {
        sv[e]     = (short)f2bf(P[j][0][e]);
        sv[4 + e] = (short)f2bf(P[j][1][e]);
      }
      ((bf16x8*)s_msgF)[f * 64 + lane] = sv;
    }
    barrier_lds();   // B1: msgF visible; also fences PV(it-1) reads vs kv writes below

    // k/v projection: 32 MFMA, progressive A loads (low reg pressure)
    {
      f32x4 ak[2][2], av[2][2];
#pragma unroll
      for (int mt = 0; mt < 2; ++mt)
#pragma unroll
        for (int nt = 0; nt < 2; ++nt) {
          ak[mt][nt] = (f32x4){kb2[nt], kb2[nt], kb2[nt], kb2[nt]};
          av[mt][nt] = (f32x4){vb2[nt], vb2[nt], vb2[nt], vb2[nt]};
        }
#pragma unroll
      for (int ks = 0; ks < 4; ++ks) {
        const bf16x8 a0 = ((const bf16x8*)s_msgF)[ks * 64 + lane];        // mt=0
        const bf16x8 a1 = ((const bf16x8*)s_msgF)[(4 + ks) * 64 + lane];  // mt=1
#pragma unroll
        for (int nt = 0; nt < 2; ++nt) {
          ak[0][nt] = __builtin_amdgcn_mfma_f32_16x16x32_bf16(a0, Bk[nt][ks], ak[0][nt], 0, 0, 0);
          av[0][nt] = __builtin_amdgcn_mfma_f32_16x16x32_bf16(a0, Bv[nt][ks], av[0][nt], 0, 0, 0);
          ak[1][nt] = __builtin_amdgcn_mfma_f32_16x16x32_bf16(a1, Bk[nt][ks], ak[1][nt], 0, 0, 0);
          av[1][nt] = __builtin_amdgcn_mfma_f32_16x16x32_bf16(a1, Bv[nt][ks], av[1][nt], 0, 0, 0);
        }
      }
#pragma unroll
      for (int mt = 0; mt < 2; ++mt)
#pragma unroll
        for (int nt = 0; nt < 2; ++nt) {
          const int col = n0 + nt * 16 + lm;
          const int row0 = mt * 16 + lg * 4;
#pragma unroll
          for (int r = 0; r < 4; ++r) {
            s_k[(row0 + r) * KSTR + col] = f2bf(ak[mt][nt][r]);
            s_v[(row0 + r) * KSTR + col] = f2bf(fmaxf(av[mt][nt][r], 0.f));
          }
        }
    }

    // prefetch msg(token it+1): issued here, rides across B2/B3 (no vmcnt drain),
    // waited only at next iteration's stage use.
    if (it + 1 < TPB) {
#pragma unroll
      for (int j = 0; j < 2; ++j) {
        const int f = j * 4 + w, mt = f >> 2, ks = f & 3;
        const float* mp = msg + (size_t)(tok + 1) * (NA * HID) + (mt * 16 + lm) * HID + ks * 32 + lg * 8;
        P[j][0] = *(const f32x4*)mp; P[j][1] = *(const f32x4*)(mp + 4);
      }
    }
    barrier_lds();   // B2: k/v visible

    // scores + masked softmax: thread (head = t>>5, a = t&31)
    {
      const int head = t >> 5, a = t & 31;
      const f32x4* qr = (const f32x4*)(s_qall + it * HID + head * 16);
      const bf16x8 k0 = *(const bf16x8*)&s_k[a * KSTR + head * 16];
      const bf16x8 k1 = *(const bf16x8*)&s_k[a * KSTR + head * 16 + 8];
      const f32x4 q0 = qr[0], q1 = qr[1], q2 = qr[2], q3 = qr[3];
      float sc = 0.f;
#pragma unroll
      for (int e = 0; e < 4; ++e) {
        sc = fmaf(q0[e], bf2f((unsigned short)k0[e]), sc);
        sc = fmaf(q1[e], bf2f((unsigned short)k0[4 + e]), sc);
        sc = fmaf(q2[e], bf2f((unsigned short)k1[e]), sc);
        sc = fmaf(q3[e], bf2f((unsigned short)k1[4 + e]), sc);
      }
      const float mk = mask[(size_t)tok * NA + a];
      sc = sc * 0.25f * mk;
      if (sc == 0.0f) sc = -1000000.0f;   // exact reference semantics
      float mx = sc;
#pragma unroll
      for (int off = 16; off; off >>= 1) mx = fmaxf(mx, __shfl_xor(mx, off));
      const float ex = __expf(sc - mx);
      float sm = ex;
#pragma unroll
      for (int off = 16; off; off >>= 1) sm += __shfl_xor(sm, off);
      s_p[head * NA + a] = ex / sm * mk;  // softmax * mask
    }
    barrier_lds();   // B3: s_p visible

    // PV: 256 threads, thread (o = t>>1, half = t&1) sums 16 a's; shfl-combine
    {
      const int o = t >> 1, half = t & 1;
      const int head = o >> 4;
      const float* pr = s_p + head * NA + half * 16;
      float ctx = 0.f;
#pragma unroll
      for (int i = 0; i < 16; ++i)
        ctx = fmaf(pr[i], bf2f(s_v[(half * 16 + i) * KSTR + o]), ctx);
      ctx += __shfl_xor(ctx, 1);
      if (half == 0) {
        // ctx A-frag: frag = o>>5, kg = (o>>3)&3, m = it, e = o&7
        ((unsigned short*)s_ctxF)[(((o >> 5) * 64) + ((o >> 3) & 3) * 16 + it) * 8 + (o & 7)] = f2bf(ctx);
      }
    }
    // next stage writes msgF only (kv readers fenced by this iter's B2)
  }
  __syncthreads();   // ctxF complete

  // ---- batched d projection (Bd transient) ----
  {
    bf16x8 Bd[2][4];
    float db2[2];
#pragma unroll
    for (int nt = 0; nt < 2; ++nt) {
      const int col = n0 + nt * 16 + lm;
      db2[nt] = db[col];
#pragma unroll
      for (int ks = 0; ks < 4; ++ks) {
        bf16x8 bd;
#pragma unroll
        for (int e = 0; e < 8; ++e)
          bd[e] = (short)f2bf(dW[(size_t)(ks * 32 + lg * 8 + e) * HID + col]);
        Bd[nt][ks] = bd;
      }
    }
    f32x4 accd[2];
#pragma unroll
    for (int nt = 0; nt < 2; ++nt) accd[nt] = (f32x4){db2[nt], db2[nt], db2[nt], db2[nt]};
#pragma unroll
    for (int ks = 0; ks < 4; ++ks) {
      const bf16x8 a = ((const bf16x8*)s_ctxF)[ks * 64 + lane];
#pragma unroll
      for (int nt = 0; nt < 2; ++nt)
        accd[nt] = __builtin_amdgcn_mfma_f32_16x16x32_bf16(a, Bd[nt][ks], accd[nt], 0, 0, 0);
    }
    __syncthreads();  // hF region dead everywhere before dall writes (union safety)
#pragma unroll
    for (int nt = 0; nt < 2; ++nt)
#pragma unroll
      for (int r = 0; r < 4; ++r) {
        const int row = lg * 4 + r;
        if (row < TPB) s_dall[row * HID + n0 + nt * 16 + lm] = accd[nt][r];
      }
  }
  __syncthreads();

  // ---- residual (h reloaded from global) + layernorm ----
  {
    const int row = t >> 5, seg = t & 31;
    const f32x4 xd = *(const f32x4*)(s_dall + row * HID + seg * 4);
    const f32x4 xh = *(const f32x4*)(h + (size_t)(tok0 + row) * HID + seg * 4);
    float x[4];
    float s1 = 0.f, s2 = 0.f;
#pragma unroll
    for (int e = 0; e < 4; ++e) { x[e] = xd[e] + xh[e]; s1 += x[e]; s2 += x[e] * x[e]; }
#pragma unroll
    for (int off = 16; off; off >>= 1) { s1 += __shfl_xor(s1, off); s2 += __shfl_xor(s2, off); }
    const float u   = s1 * (1.f / 128.f);
    const float var = s2 * (1.f / 128.f) - u * u;
    const float rs  = rsqrtf(var + 1e-12f);
    const f32x4 w4 = *(const f32x4*)(lnw + seg * 4);
    const f32x4 b4 = *(const f32x4*)(lnb + seg * 4);
    f32x4 y;
#pragma unroll
    for (int e = 0; e < 4; ++e) y[e] = w4[e] * ((x[e] - u) * rs) + b4[e];
    *(f32x4*)(out + (size_t)(tok0 + row) * HID + seg * 4) = y;
  }
}

extern "C" void kernel_launch(void* const* d_in, const int* in_sizes, int n_in,
                              void* d_out, int out_size, void* d_ws, size_t ws_size,
                              hipStream_t stream) {
  const float* h    = (const float*)d_in[0];
  const float* msg  = (const float*)d_in[1];
  const float* mask = (const float*)d_in[2];
  const float* qW   = (const float*)d_in[3];
  const float* qb   = (const float*)d_in[4];
  const float* kW   = (const float*)d_in[5];
  const float* kb   = (const float*)d_in[6];
  const float* vW   = (const float*)d_in[7];
  const float* vb   = (const float*)d_in[8];
  const float* dW   = (const float*)d_in[9];
  const float* db   = (const float*)d_in[10];
  const float* lnw  = (const float*)d_in[11];
  const float* lnb  = (const float*)d_in[12];
  float* out = (float*)d_out;

  const int n_tokens = in_sizes[0] / HID;   // 16384
  const int nblocks  = n_tokens / TPB;      // 2048
  soft_attn_v4<<<nblocks, 256, 0, stream>>>(
      h, msg, mask, qW, qb, kW, kb, vW, vb, dW, db, lnw, lnb, out);
}

// Round 5
// 236.204 us; speedup vs baseline: 1.4922x; 1.4922x over previous
//
#include <hip/hip_runtime.h>

typedef short  bf16x8 __attribute__((ext_vector_type(8)));
typedef float  f32x4  __attribute__((ext_vector_type(4)));

#define NA   32
#define HID  128
#define TPB  8
#define KSTR 136   // ushort stride, 272B rows: 16B-aligned for b128 reads

__device__ __forceinline__ unsigned short f2bf(float f) {
  unsigned int u = __float_as_uint(f);
  return (unsigned short)((u + 0x7FFFu + ((u >> 16) & 1u)) >> 16);  // RNE
}
__device__ __forceinline__ float bf2f(unsigned short s) {
  return __uint_as_float(((unsigned int)s) << 16);
}
// LDS-only barrier: does NOT drain vmcnt, so global prefetch loads stay in
// flight across it (the only cross-wave hazard in the main loop is LDS: msgF).
__device__ __forceinline__ void barrier_lds() {
  asm volatile("s_waitcnt lgkmcnt(0)" ::: "memory");
  __builtin_amdgcn_s_barrier();
  asm volatile("" ::: "memory");
}

__global__ __launch_bounds__(256, 3) void soft_attn_v5(
    const float* __restrict__ h, const float* __restrict__ msg,
    const float* __restrict__ mask,
    const float* __restrict__ qW, const float* __restrict__ qb,
    const float* __restrict__ kW, const float* __restrict__ kb,
    const float* __restrict__ vW, const float* __restrict__ vb,
    const float* __restrict__ dW, const float* __restrict__ db,
    const float* __restrict__ lnw, const float* __restrict__ lnb,
    float* __restrict__ out)
{
  const int t    = threadIdx.x;
  const int lane = t & 63;
  const int w    = t >> 6;        // wave id; owns output cols [32w, 32w+32), heads {2w,2w+1}
  const int lm   = lane & 15;
  const int lg   = lane >> 4;
  const int n0   = w * 32;
  const int tok0 = blockIdx.x * TPB;

  // Wave-privacy: s_k/s_v/s_qall (by col), s_p (by head), s_ctxF (by col) are
  // written AND read only by the owning wave -> in-wave lgkmcnt ordering only.
  // s_msgF is the single cross-wave edge -> one barrier per token, double-buffered.
  __shared__ __align__(16) short          s_msgF[2][8 * 64 * 8];  // 16 KB msg A-frags, dbuf
  __shared__ __align__(16) unsigned short s_k[NA * KSTR];         // 8704 B bf16 k
  __shared__ __align__(16) unsigned short s_v[NA * KSTR];         // 8704 B bf16 v (relu'd)
  __shared__ __align__(16) float          s_qall[TPB * HID];      // 4 KB
  __shared__ __align__(16) float          s_p[8 * NA];            // 1 KB
  __shared__ __align__(16) short          s_ctxF[4 * 64 * 8];     // 4 KB ctx A-frags
  __shared__ __align__(16) char           s_un[4096];             // 4 KB: hF then dall
  short* s_hF   = (short*)s_un;
  float* s_dall = (float*)s_un;
  // total 47104 B -> 3 blocks/CU

  // ---- prologue: zero ctxF, stage h frags, prefetch msg(tok0), Bq ----
#pragma unroll
  for (int j = 0; j < 4; ++j) ((unsigned int*)s_ctxF)[t + 256 * j] = 0u;
  {
    bf16x8 sv;
#pragma unroll
    for (int e = 0; e < 8; ++e) sv[e] = 0;
    if (lm < TPB) {
      const float* hp = h + (size_t)(tok0 + lm) * HID + w * 32 + lg * 8;
      const f32x4 x0 = *(const f32x4*)hp;
      const f32x4 x1 = *(const f32x4*)(hp + 4);
#pragma unroll
      for (int e = 0; e < 4; ++e) { sv[e] = (short)f2bf(x0[e]); sv[4 + e] = (short)f2bf(x1[e]); }
    }
    ((bf16x8*)s_hF)[w * 64 + lane] = sv;   // frag f = w (K-slice), slot = kg*16+m
  }
  f32x4 P[2][2];  // msg prefetch regs: frags {w, w+4}
#pragma unroll
  for (int j = 0; j < 2; ++j) {
    const int f = j * 4 + w, mt = f >> 2, ks = f & 3;
    const float* mp = msg + (size_t)tok0 * (NA * HID) + (mt * 16 + lm) * HID + ks * 32 + lg * 8;
    P[j][0] = *(const f32x4*)mp; P[j][1] = *(const f32x4*)(mp + 4);
  }
  {
    bf16x8 Bq[2][4];
    float qb2[2];
#pragma unroll
    for (int nt = 0; nt < 2; ++nt) {
      const int col = n0 + nt * 16 + lm;
      qb2[nt] = qb[col];
#pragma unroll
      for (int ks = 0; ks < 4; ++ks) {
        bf16x8 bq;
#pragma unroll
        for (int e = 0; e < 8; ++e)
          bq[e] = (short)f2bf(qW[(size_t)(ks * 32 + lg * 8 + e) * HID + col]);
        Bq[nt][ks] = bq;
      }
    }
    __syncthreads();   // hF + ctxF-zero ready
    f32x4 accq[2];
#pragma unroll
    for (int nt = 0; nt < 2; ++nt) accq[nt] = (f32x4){qb2[nt], qb2[nt], qb2[nt], qb2[nt]};
#pragma unroll
    for (int ks = 0; ks < 4; ++ks) {
      const bf16x8 a = ((const bf16x8*)s_hF)[ks * 64 + lane];
#pragma unroll
      for (int nt = 0; nt < 2; ++nt)
        accq[nt] = __builtin_amdgcn_mfma_f32_16x16x32_bf16(a, Bq[nt][ks], accq[nt], 0, 0, 0);
    }
#pragma unroll
    for (int nt = 0; nt < 2; ++nt)
#pragma unroll
      for (int r = 0; r < 4; ++r) {
        const int row = lg * 4 + r;
        if (row < TPB) s_qall[row * HID + n0 + nt * 16 + lm] = accq[nt][r];
      }
  }

  // ---- persistent k/v weight fragments (64 VGPR) ----
  bf16x8 Bk[2][4], Bv[2][4];
  float kb2[2], vb2[2];
#pragma unroll
  for (int nt = 0; nt < 2; ++nt) {
    const int col = n0 + nt * 16 + lm;
    kb2[nt] = kb[col]; vb2[nt] = vb[col];
#pragma unroll
    for (int ks = 0; ks < 4; ++ks) {
      bf16x8 bk, bv;
#pragma unroll
      for (int e = 0; e < 8; ++e) {
        const size_t r = (size_t)(ks * 32 + lg * 8 + e) * HID + col;
        bk[e] = (short)f2bf(kW[r]); bv[e] = (short)f2bf(vW[r]);
      }
      Bk[nt][ks] = bk; Bv[nt][ks] = bv;
    }
  }

  // ---- main loop: ONE barrier per token ----
#pragma unroll 2
  for (int it = 0; it < TPB; ++it) {
    const int tok = tok0 + it;
    const int buf = it & 1;

    // stage own frags {w, w+4} from P into s_msgF[buf]
#pragma unroll
    for (int j = 0; j < 2; ++j) {
      const int f = j * 4 + w;
      bf16x8 sv;
#pragma unroll
      for (int e = 0; e < 4; ++e) {
        sv[e]     = (short)f2bf(P[j][0][e]);
        sv[4 + e] = (short)f2bf(P[j][1][e]);
      }
      ((bf16x8*)(&s_msgF[buf][0]))[f * 64 + lane] = sv;
    }
    barrier_lds();   // B1: all stages visible (dbuf makes laggard readers of buf^1 safe)

    // k/v projection: 32 MFMA from msgF[buf] + reg weights -> own cols of s_k/s_v
    {
      f32x4 ak[2][2], av[2][2];
#pragma unroll
      for (int mt = 0; mt < 2; ++mt)
#pragma unroll
        for (int nt = 0; nt < 2; ++nt) {
          ak[mt][nt] = (f32x4){kb2[nt], kb2[nt], kb2[nt], kb2[nt]};
          av[mt][nt] = (f32x4){vb2[nt], vb2[nt], vb2[nt], vb2[nt]};
        }
#pragma unroll
      for (int ks = 0; ks < 4; ++ks) {
        const bf16x8 a0 = ((const bf16x8*)(&s_msgF[buf][0]))[ks * 64 + lane];        // mt=0
        const bf16x8 a1 = ((const bf16x8*)(&s_msgF[buf][0]))[(4 + ks) * 64 + lane];  // mt=1
#pragma unroll
        for (int nt = 0; nt < 2; ++nt) {
          ak[0][nt] = __builtin_amdgcn_mfma_f32_16x16x32_bf16(a0, Bk[nt][ks], ak[0][nt], 0, 0, 0);
          av[0][nt] = __builtin_amdgcn_mfma_f32_16x16x32_bf16(a0, Bv[nt][ks], av[0][nt], 0, 0, 0);
          ak[1][nt] = __builtin_amdgcn_mfma_f32_16x16x32_bf16(a1, Bk[nt][ks], ak[1][nt], 0, 0, 0);
          av[1][nt] = __builtin_amdgcn_mfma_f32_16x16x32_bf16(a1, Bv[nt][ks], av[1][nt], 0, 0, 0);
        }
      }
#pragma unroll
      for (int mt = 0; mt < 2; ++mt)
#pragma unroll
        for (int nt = 0; nt < 2; ++nt) {
          const int col  = n0 + nt * 16 + lm;
          const int row0 = mt * 16 + lg * 4;
#pragma unroll
          for (int r = 0; r < 4; ++r) {
            s_k[(row0 + r) * KSTR + col] = f2bf(ak[mt][nt][r]);
            s_v[(row0 + r) * KSTR + col] = f2bf(fmaxf(av[mt][nt][r], 0.f));
          }
        }
    }

    // prefetch msg(tok+1): rides across the rest of the iteration (no vmcnt drain)
    if (it + 1 < TPB) {
#pragma unroll
      for (int j = 0; j < 2; ++j) {
        const int f = j * 4 + w, mt = f >> 2, ks = f & 3;
        const float* mp = msg + (size_t)(tok + 1) * (NA * HID) + (mt * 16 + lm) * HID + ks * 32 + lg * 8;
        P[j][0] = *(const f32x4*)mp; P[j][1] = *(const f32x4*)(mp + 4);
      }
    }

    // scores + masked softmax: wave-private (head = 2w + lane>>5, a = lane&31)
    {
      const int hh = lane >> 5, a = lane & 31;
      const int head = 2 * w + hh;
      const f32x4* qr = (const f32x4*)(s_qall + it * HID + head * 16);
      const bf16x8 k0 = *(const bf16x8*)&s_k[a * KSTR + head * 16];
      const bf16x8 k1 = *(const bf16x8*)&s_k[a * KSTR + head * 16 + 8];
      const f32x4 q0 = qr[0], q1 = qr[1], q2 = qr[2], q3 = qr[3];
      float sc = 0.f;
#pragma unroll
      for (int e = 0; e < 4; ++e) {
        sc = fmaf(q0[e], bf2f((unsigned short)k0[e]), sc);
        sc = fmaf(q1[e], bf2f((unsigned short)k0[4 + e]), sc);
        sc = fmaf(q2[e], bf2f((unsigned short)k1[e]), sc);
        sc = fmaf(q3[e], bf2f((unsigned short)k1[4 + e]), sc);
      }
      const float mk = mask[(size_t)tok * NA + a];
      sc = sc * 0.25f * mk;
      if (sc == 0.0f) sc = -1000000.0f;   // exact reference semantics
      float mx = sc;
#pragma unroll
      for (int off = 16; off; off >>= 1) mx = fmaxf(mx, __shfl_xor(mx, off));
      const float ex = __expf(sc - mx);
      float sm = ex;
#pragma unroll
      for (int off = 16; off; off >>= 1) sm += __shfl_xor(sm, off);
      s_p[head * NA + a] = ex / sm * mk;  // softmax * mask (own head rows)
    }

    // PV: wave-private cols o in [n0, n0+32); lane = 2*(o-n0)+half
    {
      const int o = n0 + (lane >> 1), half = lane & 1;
      const int head = o >> 4;
      const float* pr = s_p + head * NA + half * 16;
      float ctx = 0.f;
#pragma unroll
      for (int i = 0; i < 16; ++i)
        ctx = fmaf(pr[i], bf2f(s_v[(half * 16 + i) * KSTR + o]), ctx);
      ctx += __shfl_xor(ctx, 1);
      if (half == 0) {
        // ctx A-frag: frag = o>>5, kg = (o>>3)&3, m = it, e = o&7
        ((unsigned short*)s_ctxF)[(((o >> 5) * 64) + ((o >> 3) & 3) * 16 + it) * 8 + (o & 7)] = f2bf(ctx);
      }
    }
  }
  __syncthreads();   // ctxF complete (cross-wave for d-proj)

  // ---- batched d projection (Bd transient) ----
  {
    bf16x8 Bd[2][4];
    float db2[2];
#pragma unroll
    for (int nt = 0; nt < 2; ++nt) {
      const int col = n0 + nt * 16 + lm;
      db2[nt] = db[col];
#pragma unroll
      for (int ks = 0; ks < 4; ++ks) {
        bf16x8 bd;
#pragma unroll
        for (int e = 0; e < 8; ++e)
          bd[e] = (short)f2bf(dW[(size_t)(ks * 32 + lg * 8 + e) * HID + col]);
        Bd[nt][ks] = bd;
      }
    }
    f32x4 accd[2];
#pragma unroll
    for (int nt = 0; nt < 2; ++nt) accd[nt] = (f32x4){db2[nt], db2[nt], db2[nt], db2[nt]};
#pragma unroll
    for (int ks = 0; ks < 4; ++ks) {
      const bf16x8 a = ((const bf16x8*)s_ctxF)[ks * 64 + lane];
#pragma unroll
      for (int nt = 0; nt < 2; ++nt)
        accd[nt] = __builtin_amdgcn_mfma_f32_16x16x32_bf16(a, Bd[nt][ks], accd[nt], 0, 0, 0);
    }
    // s_un: hF dead since prologue (last read at q-MFMA, __syncthreads passed since)
#pragma unroll
    for (int nt = 0; nt < 2; ++nt)
#pragma unroll
      for (int r = 0; r < 4; ++r) {
        const int row = lg * 4 + r;
        if (row < TPB) s_dall[row * HID + n0 + nt * 16 + lm] = accd[nt][r];
      }
  }
  __syncthreads();

  // ---- residual (h reloaded from global) + layernorm ----
  {
    const int row = t >> 5, seg = t & 31;
    const f32x4 xd = *(const f32x4*)(s_dall + row * HID + seg * 4);
    const f32x4 xh = *(const f32x4*)(h + (size_t)(tok0 + row) * HID + seg * 4);
    float x[4];
    float s1 = 0.f, s2 = 0.f;
#pragma unroll
    for (int e = 0; e < 4; ++e) { x[e] = xd[e] + xh[e]; s1 += x[e]; s2 += x[e] * x[e]; }
#pragma unroll
    for (int off = 16; off; off >>= 1) { s1 += __shfl_xor(s1, off); s2 += __shfl_xor(s2, off); }
    const float u   = s1 * (1.f / 128.f);
    const float var = s2 * (1.f / 128.f) - u * u;
    const float rs  = rsqrtf(var + 1e-12f);
    const f32x4 w4 = *(const f32x4*)(lnw + seg * 4);
    const f32x4 b4 = *(const f32x4*)(lnb + seg * 4);
    f32x4 y;
#pragma unroll
    for (int e = 0; e < 4; ++e) y[e] = w4[e] * ((x[e] - u) * rs) + b4[e];
    *(f32x4*)(out + (size_t)(tok0 + row) * HID + seg * 4) = y;
  }
}

extern "C" void kernel_launch(void* const* d_in, const int* in_sizes, int n_in,
                              void* d_out, int out_size, void* d_ws, size_t ws_size,
                              hipStream_t stream) {
  const float* h    = (const float*)d_in[0];
  const float* msg  = (const float*)d_in[1];
  const float* mask = (const float*)d_in[2];
  const float* qW   = (const float*)d_in[3];
  const float* qb   = (const float*)d_in[4];
  const float* kW   = (const float*)d_in[5];
  const float* kb   = (const float*)d_in[6];
  const float* vW   = (const float*)d_in[7];
  const float* vb   = (const float*)d_in[8];
  const float* dW   = (const float*)d_in[9];
  const float* db   = (const float*)d_in[10];
  const float* lnw  = (const float*)d_in[11];
  const float* lnb  = (const float*)d_in[12];
  float* out = (float*)d_out;

  const int n_tokens = in_sizes[0] / HID;   // 16384
  const int nblocks  = n_tokens / TPB;      // 2048
  soft_attn_v5<<<nblocks, 256, 0, stream>>>(
      h, msg, mask, qW, qb, kW, kb, vW, vb, dW, db, lnw, lnb, out);
}

// Round 6
// 140.932 us; speedup vs baseline: 2.5010x; 1.6760x over previous
//
#include <hip/hip_runtime.h>

typedef short  bf16x8 __attribute__((ext_vector_type(8)));
typedef float  f32x4  __attribute__((ext_vector_type(4)));

#define NA   32
#define HID  128
#define TPB  8
#define KSTR 136   // ushort stride, 272B rows: 16B-aligned for b128 reads

__device__ __forceinline__ unsigned short f2bf(float f) {
  unsigned int u = __float_as_uint(f);
  return (unsigned short)((u + 0x7FFFu + ((u >> 16) & 1u)) >> 16);  // RNE
}
__device__ __forceinline__ float bf2f(unsigned short s) {
  return __uint_as_float(((unsigned int)s) << 16);
}
// LDS-only barrier: does NOT drain vmcnt, so global prefetch loads stay in
// flight across it (the only cross-wave hazard in the main loop is LDS: msgF).
__device__ __forceinline__ void barrier_lds() {
  asm volatile("s_waitcnt lgkmcnt(0)" ::: "memory");
  __builtin_amdgcn_s_barrier();
  asm volatile("" ::: "memory");
}

__global__ __launch_bounds__(256, 2) void soft_attn_v6(
    const float* __restrict__ h, const float* __restrict__ msg,
    const float* __restrict__ mask,
    const float* __restrict__ qW, const float* __restrict__ qb,
    const float* __restrict__ kW, const float* __restrict__ kb,
    const float* __restrict__ vW, const float* __restrict__ vb,
    const float* __restrict__ dW, const float* __restrict__ db,
    const float* __restrict__ lnw, const float* __restrict__ lnb,
    float* __restrict__ out)
{
  const int t    = threadIdx.x;
  const int lane = t & 63;
  const int w    = t >> 6;        // wave id; owns output cols [32w, 32w+32), heads {2w,2w+1}
  const int lm   = lane & 15;
  const int lg   = lane >> 4;
  const int n0   = w * 32;
  const int tok0 = blockIdx.x * TPB;

  // Wave-privacy: s_k/s_v/s_qall (by col), s_p (by head), s_ctxF (by col) are
  // written AND read only by the owning wave -> in-wave lgkmcnt ordering only.
  // s_msgF is the single cross-wave edge -> one barrier per token, double-buffered.
  __shared__ __align__(16) short          s_msgF[2][8 * 64 * 8];  // 16 KB msg A-frags, dbuf
  __shared__ __align__(16) unsigned short s_k[NA * KSTR];         // 8704 B bf16 k
  __shared__ __align__(16) unsigned short s_v[NA * KSTR];         // 8704 B bf16 v (relu'd)
  __shared__ __align__(16) float          s_qall[TPB * HID];      // 4 KB
  __shared__ __align__(16) float          s_p[8 * NA];            // 1 KB
  __shared__ __align__(16) short          s_ctxF[4 * 64 * 8];     // 4 KB ctx A-frags
  __shared__ __align__(16) char           s_un[4096];             // 4 KB: hF then dall
  short* s_hF   = (short*)s_un;
  float* s_dall = (float*)s_un;

  // ---- msg prefetch regs: P[d] holds token with parity d; depth-2 pipeline ----
  f32x4 P[2][2][2];
#pragma unroll
  for (int d = 0; d < 2; ++d)
#pragma unroll
    for (int j = 0; j < 2; ++j) {
      const int f = j * 4 + w, mt = f >> 2, ks = f & 3;
      const float* mp = msg + (size_t)(tok0 + d) * (NA * HID) + (mt * 16 + lm) * HID + ks * 32 + lg * 8;
      P[d][j][0] = *(const f32x4*)mp; P[d][j][1] = *(const f32x4*)(mp + 4);
    }

  // ---- mask preload: lane's a = lane&31, all TPB tokens (8 VGPR) ----
  float m8[TPB];
#pragma unroll
  for (int i = 0; i < TPB; ++i) m8[i] = mask[(size_t)(tok0 + i) * NA + (lane & 31)];

  // ---- prologue: zero ctxF, stage h frags, Bq, q-projection ----
#pragma unroll
  for (int j = 0; j < 4; ++j) ((unsigned int*)s_ctxF)[t + 256 * j] = 0u;
  {
    bf16x8 sv;
#pragma unroll
    for (int e = 0; e < 8; ++e) sv[e] = 0;
    if (lm < TPB) {
      const float* hp = h + (size_t)(tok0 + lm) * HID + w * 32 + lg * 8;
      const f32x4 x0 = *(const f32x4*)hp;
      const f32x4 x1 = *(const f32x4*)(hp + 4);
#pragma unroll
      for (int e = 0; e < 4; ++e) { sv[e] = (short)f2bf(x0[e]); sv[4 + e] = (short)f2bf(x1[e]); }
    }
    ((bf16x8*)s_hF)[w * 64 + lane] = sv;   // frag f = w (K-slice), slot = kg*16+m
  }
  {
    bf16x8 Bq[2][4];
    float qb2[2];
#pragma unroll
    for (int nt = 0; nt < 2; ++nt) {
      const int col = n0 + nt * 16 + lm;
      qb2[nt] = qb[col];
#pragma unroll
      for (int ks = 0; ks < 4; ++ks) {
        bf16x8 bq;
#pragma unroll
        for (int e = 0; e < 8; ++e)
          bq[e] = (short)f2bf(qW[(size_t)(ks * 32 + lg * 8 + e) * HID + col]);
        Bq[nt][ks] = bq;
      }
    }
    __syncthreads();   // hF + ctxF-zero ready
    f32x4 accq[2];
#pragma unroll
    for (int nt = 0; nt < 2; ++nt) accq[nt] = (f32x4){qb2[nt], qb2[nt], qb2[nt], qb2[nt]};
#pragma unroll
    for (int ks = 0; ks < 4; ++ks) {
      const bf16x8 a = ((const bf16x8*)s_hF)[ks * 64 + lane];
#pragma unroll
      for (int nt = 0; nt < 2; ++nt)
        accq[nt] = __builtin_amdgcn_mfma_f32_16x16x32_bf16(a, Bq[nt][ks], accq[nt], 0, 0, 0);
    }
#pragma unroll
    for (int nt = 0; nt < 2; ++nt)
#pragma unroll
      for (int r = 0; r < 4; ++r) {
        const int row = lg * 4 + r;
        if (row < TPB) s_qall[row * HID + n0 + nt * 16 + lm] = accq[nt][r];
      }
  }

  // ---- persistent k/v weight fragments (64 VGPR) ----
  bf16x8 Bk[2][4], Bv[2][4];
  float kb2[2], vb2[2];
#pragma unroll
  for (int nt = 0; nt < 2; ++nt) {
    const int col = n0 + nt * 16 + lm;
    kb2[nt] = kb[col]; vb2[nt] = vb[col];
#pragma unroll
    for (int ks = 0; ks < 4; ++ks) {
      bf16x8 bk, bv;
#pragma unroll
      for (int e = 0; e < 8; ++e) {
        const size_t r = (size_t)(ks * 32 + lg * 8 + e) * HID + col;
        bk[e] = (short)f2bf(kW[r]); bv[e] = (short)f2bf(vW[r]);
      }
      Bk[nt][ks] = bk; Bv[nt][ks] = bv;
    }
  }

  // ---- main loop, FULLY UNROLLED (static P/m8 indexing): 1 barrier/token ----
#pragma unroll
  for (int it = 0; it < TPB; ++it) {
    const int tok = tok0 + it;
    const int buf = it & 1;

    // stage own frags {w, w+4} from P[buf] into s_msgF[buf]
#pragma unroll
    for (int j = 0; j < 2; ++j) {
      const int f = j * 4 + w;
      bf16x8 sv;
#pragma unroll
      for (int e = 0; e < 4; ++e) {
        sv[e]     = (short)f2bf(P[buf][j][0][e]);
        sv[4 + e] = (short)f2bf(P[buf][j][1][e]);
      }
      ((bf16x8*)(&s_msgF[buf][0]))[f * 64 + lane] = sv;
    }

    // immediately re-issue prefetch for token it+2 into P[buf] (consumed 2 iters later)
    if (it + 2 < TPB) {
#pragma unroll
      for (int j = 0; j < 2; ++j) {
        const int f = j * 4 + w, mt = f >> 2, ks = f & 3;
        const float* mp = msg + (size_t)(tok + 2) * (NA * HID) + (mt * 16 + lm) * HID + ks * 32 + lg * 8;
        P[buf][j][0] = *(const f32x4*)mp; P[buf][j][1] = *(const f32x4*)(mp + 4);
      }
    }
    barrier_lds();   // B1: all stages visible (dbuf: readers of buf^1 finished before this)

    // k/v projection: 32 MFMA from msgF[buf] + reg weights -> own cols of s_k/s_v
    {
      f32x4 ak[2][2], av[2][2];
#pragma unroll
      for (int mt = 0; mt < 2; ++mt)
#pragma unroll
        for (int nt = 0; nt < 2; ++nt) {
          ak[mt][nt] = (f32x4){kb2[nt], kb2[nt], kb2[nt], kb2[nt]};
          av[mt][nt] = (f32x4){vb2[nt], vb2[nt], vb2[nt], vb2[nt]};
        }
#pragma unroll
      for (int ks = 0; ks < 4; ++ks) {
        const bf16x8 a0 = ((const bf16x8*)(&s_msgF[buf][0]))[ks * 64 + lane];        // mt=0
        const bf16x8 a1 = ((const bf16x8*)(&s_msgF[buf][0]))[(4 + ks) * 64 + lane];  // mt=1
#pragma unroll
        for (int nt = 0; nt < 2; ++nt) {
          ak[0][nt] = __builtin_amdgcn_mfma_f32_16x16x32_bf16(a0, Bk[nt][ks], ak[0][nt], 0, 0, 0);
          av[0][nt] = __builtin_amdgcn_mfma_f32_16x16x32_bf16(a0, Bv[nt][ks], av[0][nt], 0, 0, 0);
          ak[1][nt] = __builtin_amdgcn_mfma_f32_16x16x32_bf16(a1, Bk[nt][ks], ak[1][nt], 0, 0, 0);
          av[1][nt] = __builtin_amdgcn_mfma_f32_16x16x32_bf16(a1, Bv[nt][ks], av[1][nt], 0, 0, 0);
        }
      }
#pragma unroll
      for (int mt = 0; mt < 2; ++mt)
#pragma unroll
        for (int nt = 0; nt < 2; ++nt) {
          const int col  = n0 + nt * 16 + lm;
          const int row0 = mt * 16 + lg * 4;
#pragma unroll
          for (int r = 0; r < 4; ++r) {
            s_k[(row0 + r) * KSTR + col] = f2bf(ak[mt][nt][r]);
            s_v[(row0 + r) * KSTR + col] = f2bf(fmaxf(av[mt][nt][r], 0.f));
          }
        }
    }

    // scores + masked softmax: wave-private (head = 2w + lane>>5, a = lane&31)
    {
      const int hh = lane >> 5, a = lane & 31;
      const int head = 2 * w + hh;
      const f32x4* qr = (const f32x4*)(s_qall + it * HID + head * 16);
      const bf16x8 k0 = *(const bf16x8*)&s_k[a * KSTR + head * 16];
      const bf16x8 k1 = *(const bf16x8*)&s_k[a * KSTR + head * 16 + 8];
      const f32x4 q0 = qr[0], q1 = qr[1], q2 = qr[2], q3 = qr[3];
      float sc = 0.f;
#pragma unroll
      for (int e = 0; e < 4; ++e) {
        sc = fmaf(q0[e], bf2f((unsigned short)k0[e]), sc);
        sc = fmaf(q1[e], bf2f((unsigned short)k0[4 + e]), sc);
        sc = fmaf(q2[e], bf2f((unsigned short)k1[e]), sc);
        sc = fmaf(q3[e], bf2f((unsigned short)k1[4 + e]), sc);
      }
      const float mk = m8[it];
      sc = sc * 0.25f * mk;
      if (sc == 0.0f) sc = -1000000.0f;   // exact reference semantics
      float mx = sc;
#pragma unroll
      for (int off = 16; off; off >>= 1) mx = fmaxf(mx, __shfl_xor(mx, off));
      const float ex = __expf(sc - mx);
      float sm = ex;
#pragma unroll
      for (int off = 16; off; off >>= 1) sm += __shfl_xor(sm, off);
      s_p[head * NA + a] = ex / sm * mk;  // softmax * mask (own head rows)
    }

    // PV: wave-private cols o in [n0, n0+32); lane = 2*(o-n0)+half
    {
      const int o = n0 + (lane >> 1), half = lane & 1;
      const int head = o >> 4;
      const float* pr = s_p + head * NA + half * 16;
      float ctx = 0.f;
#pragma unroll
      for (int i = 0; i < 16; ++i)
        ctx = fmaf(pr[i], bf2f(s_v[(half * 16 + i) * KSTR + o]), ctx);
      ctx += __shfl_xor(ctx, 1);
      if (half == 0) {
        // ctx A-frag: frag = o>>5, kg = (o>>3)&3, m = it, e = o&7
        ((unsigned short*)s_ctxF)[(((o >> 5) * 64) + ((o >> 3) & 3) * 16 + it) * 8 + (o & 7)] = f2bf(ctx);
      }
    }
  }
  __syncthreads();   // ctxF complete (cross-wave for d-proj)

  // ---- batched d projection (Bd transient) ----
  {
    bf16x8 Bd[2][4];
    float db2[2];
#pragma unroll
    for (int nt = 0; nt < 2; ++nt) {
      const int col = n0 + nt * 16 + lm;
      db2[nt] = db[col];
#pragma unroll
      for (int ks = 0; ks < 4; ++ks) {
        bf16x8 bd;
#pragma unroll
        for (int e = 0; e < 8; ++e)
          bd[e] = (short)f2bf(dW[(size_t)(ks * 32 + lg * 8 + e) * HID + col]);
        Bd[nt][ks] = bd;
      }
    }
    f32x4 accd[2];
#pragma unroll
    for (int nt = 0; nt < 2; ++nt) accd[nt] = (f32x4){db2[nt], db2[nt], db2[nt], db2[nt]};
#pragma unroll
    for (int ks = 0; ks < 4; ++ks) {
      const bf16x8 a = ((const bf16x8*)s_ctxF)[ks * 64 + lane];
#pragma unroll
      for (int nt = 0; nt < 2; ++nt)
        accd[nt] = __builtin_amdgcn_mfma_f32_16x16x32_bf16(a, Bd[nt][ks], accd[nt], 0, 0, 0);
    }
    // s_un: hF dead since prologue (last read at q-MFMA, __syncthreads passed since)
#pragma unroll
    for (int nt = 0; nt < 2; ++nt)
#pragma unroll
      for (int r = 0; r < 4; ++r) {
        const int row = lg * 4 + r;
        if (row < TPB) s_dall[row * HID + n0 + nt * 16 + lm] = accd[nt][r];
      }
  }
  __syncthreads();

  // ---- residual (h reloaded from global) + layernorm ----
  {
    const int row = t >> 5, seg = t & 31;
    const f32x4 xd = *(const f32x4*)(s_dall + row * HID + seg * 4);
    const f32x4 xh = *(const f32x4*)(h + (size_t)(tok0 + row) * HID + seg * 4);
    float x[4];
    float s1 = 0.f, s2 = 0.f;
#pragma unroll
    for (int e = 0; e < 4; ++e) { x[e] = xd[e] + xh[e]; s1 += x[e]; s2 += x[e] * x[e]; }
#pragma unroll
    for (int off = 16; off; off >>= 1) { s1 += __shfl_xor(s1, off); s2 += __shfl_xor(s2, off); }
    const float u   = s1 * (1.f / 128.f);
    const float var = s2 * (1.f / 128.f) - u * u;
    const float rs  = rsqrtf(var + 1e-12f);
    const f32x4 w4 = *(const f32x4*)(lnw + seg * 4);
    const f32x4 b4 = *(const f32x4*)(lnb + seg * 4);
    f32x4 y;
#pragma unroll
    for (int e = 0; e < 4; ++e) y[e] = w4[e] * ((x[e] - u) * rs) + b4[e];
    *(f32x4*)(out + (size_t)(tok0 + row) * HID + seg * 4) = y;
  }
}

extern "C" void kernel_launch(void* const* d_in, const int* in_sizes, int n_in,
                              void* d_out, int out_size, void* d_ws, size_t ws_size,
                              hipStream_t stream) {
  const float* h    = (const float*)d_in[0];
  const float* msg  = (const float*)d_in[1];
  const float* mask = (const float*)d_in[2];
  const float* qW   = (const float*)d_in[3];
  const float* qb   = (const float*)d_in[4];
  const float* kW   = (const float*)d_in[5];
  const float* kb   = (const float*)d_in[6];
  const float* vW   = (const float*)d_in[7];
  const float* vb   = (const float*)d_in[8];
  const float* dW   = (const float*)d_in[9];
  const float* db   = (const float*)d_in[10];
  const float* lnw  = (const float*)d_in[11];
  const float* lnb  = (const float*)d_in[12];
  float* out = (float*)d_out;

  const int n_tokens = in_sizes[0] / HID;   // 16384
  const int nblocks  = n_tokens / TPB;      // 2048
  soft_attn_v6<<<nblocks, 256, 0, stream>>>(
      h, msg, mask, qW, qb, kW, kb, vW, vb, dW, db, lnw, lnb, out);
}